// Round 13
// baseline (1203.903 us; speedup 1.0000x reference)
//
#include <hip/hip_runtime.h>
#include <math.h>

#define HWN 4096
#define Bn 4
#define Tn 8

typedef __attribute__((ext_vector_type(8))) _Float16 f16x8;
typedef __attribute__((ext_vector_type(4))) float floatx4;

// fast HW transcendentals: v_exp_f32 / v_rcp_f32 (no OCML branchy calls)
__device__ __forceinline__ float fexp2_(float x) { return __builtin_amdgcn_exp2f(x); }
__device__ __forceinline__ float frcp_(float x)  { return __builtin_amdgcn_rcpf(x); }
__device__ __forceinline__ float sigmoidf_(float v) {
    return frcp_(1.f + fexp2_(v * -1.44269504089f));
}
__device__ __forceinline__ float tanhf_(float v) {
    float vc = fminf(fmaxf(v, -15.f), 15.f);      // avoid inf/inf NaN
    float t = fexp2_(vc * 2.88539008178f);        // e^(2v)
    return (t - 1.f) * frcp_(t + 1.f);
}

// split 8 fp32 -> f16 hi/lo vectors (value = hi + lo, ~22-bit effective)
__device__ __forceinline__ void split8(const float* vv, f16x8* hi, f16x8* lo) {
#pragma unroll
    for (int j = 0; j < 8; ++j) {
        _Float16 h = (_Float16)vv[j];
        (*hi)[j] = h;
        (*lo)[j] = (_Float16)(vv[j] - (float)h);
    }
}

// ---------------------------------------------------------------------------
// Weight prep (ALL tensors in one dispatch): fp32 [Cout][Ctot][KK] ->
// A-fragment-swizzled split-f16 [plane][kk][chunk][cog][lane][j].
// blockIdx.y selects the tensor descriptor.
// ---------------------------------------------------------------------------
struct PW  { const float* W; _Float16* dst; int Ctot, Cout, nch, KK; };
struct PW8 { PW p[8]; };

__global__ __launch_bounds__(256) void prep_w_all(PW8 d)
{
    const PW e = d.p[blockIdx.y];
    const int ncog = e.Cout >> 4;
    const long total = (long)e.KK * e.nch * ncog * 512;
    for (long i = (long)blockIdx.x * 256 + threadIdx.x; i < total;
         i += (long)gridDim.x * 256) {
        int j    = (int)(i & 7);
        int lane = (int)((i >> 3) & 63);
        long r   = i >> 9;
        int f = (int)(r % ncog); r /= ncog;
        int c = (int)(r % e.nch);  r /= e.nch;
        int kk = (int)r;
        int co = f * 16 + (lane & 15);
        int ci = c * 32 + (lane >> 4) * 8 + j;
        float v = (ci < e.Ctot) ? e.W[((long)co * e.Ctot + ci) * e.KK + kk] : 0.f;
        _Float16 hi = (_Float16)v;
        e.dst[i]         = hi;
        e.dst[total + i] = (_Float16)(v - (float)hi);
    }
}

// x fp32 [b][t][16][4096] -> x_cl fp32 [t][b][px][16]
__global__ __launch_bounds__(256) void prep_x_kernel(
    const float* __restrict__ x, float* __restrict__ xcl)
{
    const int i = blockIdx.x * 256 + threadIdx.x;     // 131072 total
    const int px = i & 4095;
    const int t  = (i >> 12) & 7;
    const int b  = i >> 15;
    float* d = xcl + (((long)t * Bn + b) * HWN + px) * 16;
#pragma unroll
    for (int ch = 0; ch < 16; ++ch)
        d[ch] = x[((long)(b * 8 + t) * 16 + ch) * HWN + px];
}

// per-layer gate constants: gc[0..63]=sigmoid(tg), [64..127]=exp(-td_h),
// [128..191]=exp(-td_m). 64 threads. (precise lib exp here is fine: runs once)
__global__ void prep_gc(const float* __restrict__ tg, const float* __restrict__ tdh,
                        const float* __restrict__ tdm, float* __restrict__ gc)
{
    const int j = threadIdx.x;
    gc[j]       = 1.f / (1.f + expf(-tg[j]));
    gc[64 + j]  = expf(-tdh[j]);
    gc[128 + j] = expf(-tdm[j]);
}

// ---------------------------------------------------------------------------
// MFMA implicit-GEMM 3x3 SAME conv. fp32 channels-last activations; hi/lo
// f16 split done while writing LDS. TR = tile rows; 4 waves, G=TR/4 rows/wave.
//  - LDS tile [TR+2][18][2][40]; kx-outer tap loop with (G+2)-row reg cache
//  - weight 5-deep ring, 4-ahead prefetch; staging prefetch at end of kx==1
// EPI=0: A/B conv merged dispatch + FUSED GATES EPILOGUE. TR=8, NF=2,
//        grid (32,10,4)=1280 blocks, LDS 28.8KB -> 5 blocks/CU: the TLP
//        lever this latency-bound family responds to (r6/r12 evidence).
// EPI=1: H-conv: tanh + fused state update (+ q/k on last cell). TR=8,NF=1,
//        grid (32,4,8)=1024 blocks.
// ---------------------------------------------------------------------------
template<int EPI, int NF, int TR>
__global__ __launch_bounds__(256) void conv3m(
    const float* __restrict__ in1, int C1,
    const float* __restrict__ in2a, const float* __restrict__ in2b,
    int Ctot, int nch,
    const _Float16* __restrict__ wA, const float* __restrict__ biasA,
    float* outA, int CoutA, int ncogA,
    const _Float16* __restrict__ wB, const float* __restrict__ biasB,
    float* outB, int CoutB, int ncogB, int nA,
    float* s1, float* s2, float* s3, float* s4,
    float* s5, float* s6, float* s7, float* s8,
    const float* __restrict__ gc, int last)
{
    constexpr int G = TR / 4;                       // rows per wave
    constexpr int SLOTS = (TR + 2) * 18 * 4;        // staging slots (8ch each)
    constexpr int NS = (SLOTS + 255) / 256;         // per-thread staging iters
    __shared__ __align__(16) _Float16 ldsB[TR + 2][18][2][40];

    const int tid = threadIdx.x;
    const int ty0 = (blockIdx.x >> 2) * TR;
    const int tx0 = (blockIdx.x & 3) * 16;
    const int b   = blockIdx.z & 3;
    const int which = (EPI == 1) ? (int)(blockIdx.z >> 2)
                                 : (blockIdx.y >= (unsigned)nA ? 1 : 0);

    const float*    in2  = which ? in2b : in2a;
    const _Float16* Wf   = which ? wB : wA;
    const float*    bias = which ? biasB : biasA;
    float*          outp = which ? outB : outA;
    const int Cout = which ? CoutB : CoutA;
    const int ncog = which ? ncogB : ncogA;
    const int cog0 = (EPI == 1) ? blockIdx.y * NF
                   : (which ? (blockIdx.y - nA) * NF : blockIdx.y * NF);
    const int co0  = cog0 * 16;

    const int lane = tid & 63, wv = tid >> 6, tl = lane & 15, quad = lane >> 4;
    const int C2 = Ctot - C1;
    const long wplane = (long)9 * nch * ncog * 512;
    const float* in1b  = in1 + (long)b * HWN * C1;
    const float* in2bb = in2 + (long)b * HWN * C2;

    floatx4 acc[NF][G];
#pragma unroll
    for (int f = 0; f < NF; ++f)
#pragma unroll
        for (int g = 0; g < G; ++g) acc[f][g] = (floatx4){0.f, 0.f, 0.f, 0.f};

    // staging prefetch registers (next chunk's 8-ch groups)
    float4 pa[NS], pb[NS];
    auto prefetch = [&](int c) {
        const int c0 = c * 32;
#pragma unroll
        for (int s = 0; s < NS; ++s) {
            const int i = tid + s * 256;
            float4 va = {0.f, 0.f, 0.f, 0.f}, vb = {0.f, 0.f, 0.f, 0.f};
            if (i < SLOTS) {
                const int pxh = i >> 2, cig = i & 3;
                const int yh = pxh / 18, xh = pxh - yh * 18;
                const int y = ty0 + yh - 1, x = tx0 + xh - 1;
                const int ch = c0 + cig * 8;
                if (ch < Ctot && (unsigned)y < 64u && (unsigned)x < 64u) {
                    const float* src; long off;
                    if (ch < C1) { src = in1b;  off = (long)(y * 64 + x) * C1 + ch; }
                    else         { src = in2bb; off = (long)(y * 64 + x) * C2 + ch - C1; }
                    va = *(const float4*)(src + off);
                    vb = *(const float4*)(src + off + 4);
                }
            }
            pa[s] = va; pb[s] = vb;
        }
    };

    prefetch(0);

    for (int c = 0; c < nch; ++c) {
        // weight tap step s covers tap kk=(s%3)*3+s/3 (kx-outer order);
        // 5-deep ring, 4-ahead. Steps 0..3 issued before the barriers.
        f16x8 wh[5][NF], wl[5][NF];
#define LOADW(S, BUF)                                                           \
        {                                                                       \
            const int kk_ = ((S) % 3) * 3 + (S) / 3;                            \
            const long wo_ = ((long)(kk_ * nch + c) * ncog + cog0) * 512 + lane * 8; \
            _Pragma("unroll")                                                   \
            for (int f = 0; f < NF; ++f) {                                      \
                wh[BUF][f] = *(const f16x8*)(Wf + wo_ + (long)f * 512);         \
                wl[BUF][f] = *(const f16x8*)(Wf + wplane + wo_ + (long)f * 512);\
            }                                                                   \
        }
        LOADW(0, 0)
        LOADW(1, 1)
        LOADW(2, 2)
        LOADW(3, 3)

        __syncthreads();                     // protect LDS from prior readers
        // store prefetched chunk to LDS (split fp32 -> f16 hi/lo)
#pragma unroll
        for (int s = 0; s < NS; ++s) {
            const int i = tid + s * 256;
            if (i < SLOTS) {
                const int pxh = i >> 2, cig = i & 3;
                const int yh = pxh / 18, xh = pxh - yh * 18;
                float vv[8] = {pa[s].x, pa[s].y, pa[s].z, pa[s].w,
                               pb[s].x, pb[s].y, pb[s].z, pb[s].w};
                f16x8 vh, vl;
                split8(vv, &vh, &vl);
                *(f16x8*)&ldsB[yh][xh][0][cig * 8] = vh;
                *(f16x8*)&ldsB[yh][xh][1][cig * 8] = vl;
            }
        }
        __syncthreads();

        // tap loop: kx outer, (G+2)-row register cache reused across ky.
#pragma unroll
        for (int kx = 0; kx < 3; ++kx) {
            f16x8 rh[G + 2], rl[G + 2];
#pragma unroll
            for (int rr = 0; rr < G + 2; ++rr) {
                const _Float16* pB = &ldsB[wv * G + rr][tl + kx][0][quad * 8];
                rh[rr] = *(const f16x8*)pB;
                rl[rr] = *(const f16x8*)(pB + 40);
            }
#pragma unroll
            for (int ky = 0; ky < 3; ++ky) {
                const int s = kx * 3 + ky;
                if (s < 5) LOADW(s + 4, (s + 4) % 5)
                const int cur = s % 5;
#pragma unroll
                for (int f = 0; f < NF; ++f)
#pragma unroll
                    for (int g = 0; g < G; ++g) {
                        acc[f][g] = __builtin_amdgcn_mfma_f32_16x16x32_f16(wh[cur][f], rh[g + ky], acc[f][g], 0, 0, 0);
                        acc[f][g] = __builtin_amdgcn_mfma_f32_16x16x32_f16(wh[cur][f], rl[g + ky], acc[f][g], 0, 0, 0);
                        acc[f][g] = __builtin_amdgcn_mfma_f32_16x16x32_f16(wl[cur][f], rh[g + ky], acc[f][g], 0, 0, 0);
                    }
            }
            // issue next chunk's staging loads AFTER all weight loads of
            // this chunk -> vmcnt waits on weights stay clean.
            if (kx == 1 && c + 1 < nch) prefetch(c + 1);
        }
#undef LOADW
    }

    // epilogue: C/D layout col(px)=lane&15, row(co)=quad*4+reg
    if (EPI == 0) {
        // fused gates: gid uniform per block (32-cout span never crosses 64)
        const int gid = co0 >> 6;
        const long bb64 = (long)b * HWN * 64;
        const float* dec = which ? in2b : in2a;            // m or h (base)
        const float* cs  = (const float*)s8;               // c state (base)
        float* g0   = which ? s2 : s1;                     // xm : rc
        float* g1   = which ? s4 : s3;                     // xz : z
        float* rout = which ? s7 : s6;                     // xr : r
#pragma unroll
        for (int f = 0; f < NF; ++f) {
            const int co = co0 + f * 16 + quad * 4;
            const int ch = co & 63;
            float gvc[4], dvc[4];
            if (gid < 2) {
#pragma unroll
                for (int j = 0; j < 4; ++j) {
                    gvc[j] = gc[ch + j];
                    dvc[j] = gc[(which ? 128 : 64) + ch + j];
                }
            }
#pragma unroll
            for (int g = 0; g < G; ++g) {
                const long px = (long)(ty0 + wv * G + g) * 64 + tx0 + tl;
                const long off = bb64 + px * 64 + ch;
                float vv[4];
                vv[0] = acc[f][g][0] + bias[co + 0];
                vv[1] = acc[f][g][1] + bias[co + 1];
                vv[2] = acc[f][g][2] + bias[co + 2];
                vv[3] = acc[f][g][3] + bias[co + 3];
                if (gid == 2) {
                    float ov[4];
#pragma unroll
                    for (int j = 0; j < 4; ++j) ov[j] = sigmoidf_(vv[j]);
                    *(float4*)(s5 + off) = *(float4*)ov;
                } else {
                    float4 dv = *(const float4*)(dec + off);
                    const float* dvp = (const float*)&dv;
                    float rr[4];
#pragma unroll
                    for (int j = 0; j < 4; ++j)
                        rr[j] = sigmoidf_(vv[j] * gvc[j] + dvp[j] * dvc[j]);
                    if (gid == 0) {
                        float4 sv = dv;
                        if (!which) sv = *(const float4*)(cs + off);
                        const float* svp = (const float*)&sv;
                        float outv[4];
#pragma unroll
                        for (int j = 0; j < 4; ++j) outv[j] = rr[j] * svp[j];
                        *(float4*)(g0 + off) = *(float4*)outv;
                        if (last) *(float4*)(rout + off) = *(float4*)rr;
                    } else {
                        *(float4*)(g1 + off) = *(float4*)rr;
                    }
                }
            }
        }
    } else {
        const float* zt = which ? s2 : s1;
        const float* st = which ? s4 : s3;
        float* qk = which ? s8 : s7;
#pragma unroll
        for (int f = 0; f < NF; ++f) {
            const int co = co0 + f * 16 + quad * 4;
#pragma unroll
            for (int g = 0; g < G; ++g) {
                const long px = (long)(ty0 + wv * G + g) * 64 + tx0 + tl;
                const long off = (long)b * HWN * 64 + px * 64 + co;
                float4 zv = *(const float4*)(zt + off);
                float4 sv = *(const float4*)(st + off);
                float gv[4], cn[4];
                gv[0] = tanhf_(acc[f][g][0] + bias[co + 0]);
                gv[1] = tanhf_(acc[f][g][1] + bias[co + 1]);
                gv[2] = tanhf_(acc[f][g][2] + bias[co + 2]);
                gv[3] = tanhf_(acc[f][g][3] + bias[co + 3]);
                cn[0] = zv.x * sv.x + (1.f - zv.x) * gv[0];
                cn[1] = zv.y * sv.y + (1.f - zv.y) * gv[1];
                cn[2] = zv.z * sv.z + (1.f - zv.z) * gv[2];
                cn[3] = zv.w * sv.w + (1.f - zv.w) * gv[3];
                *(float4*)(outp + off) = *(float4*)cn;
                if (last) {
                    float4 rv = *(const float4*)(s5 + off);
                    float4 xv = *(const float4*)(s6 + off);
                    qk[((long)(b * 64) + co + 0) * HWN + px] = 0.25f * (rv.x + xv.x + cn[0] + gv[0]);
                    qk[((long)(b * 64) + co + 1) * HWN + px] = 0.25f * (rv.y + xv.y + cn[1] + gv[1]);
                    qk[((long)(b * 64) + co + 2) * HWN + px] = 0.25f * (rv.z + xv.z + cn[2] + gv[2]);
                    qk[((long)(b * 64) + co + 3) * HWN + px] = 0.25f * (rv.w + xv.w + cn[3] + gv[3]);
                }
            }
        }
    }
}

// ---------------------------------------------------------------------------
// 1x1 conv (MFMA) over concat([c,m]) fp32-cl -> h = o * tanh(conv + bias).
// Each wave: 16 px x 32 couts; grid (128, B) = 512 blocks = 2048 waves.
// ---------------------------------------------------------------------------
__global__ __launch_bounds__(256) void conv1x1m(
    const float* __restrict__ cten, const float* __restrict__ mten,
    const float* __restrict__ oten,
    const _Float16* __restrict__ W, const float* __restrict__ bias,
    float* houtp)
{
    const int tid = threadIdx.x;
    const int lane = tid & 63, wv = tid >> 6, tl = lane & 15, quad = lane >> 4;
    const int b = blockIdx.y;
    const int fh = blockIdx.x & 1;                 // cout half: 0..31 / 32..63
    const int px = (blockIdx.x >> 1) * 64 + wv * 16 + tl;
    const long bb = (long)b * HWN * 64;

    // weight fragments (4 chunks x 2 cout-frags of this half, hi+lo)
    f16x8 wh[4][2], wl[4][2];
#pragma unroll
    for (int c = 0; c < 4; ++c)
#pragma unroll
        for (int f = 0; f < 2; ++f) {
            const long wo = (long)(c * 4 + fh * 2 + f) * 512 + lane * 8;
            wh[c][f] = *(const f16x8*)(W + wo);
            wl[c][f] = *(const f16x8*)(W + 8192 + wo);
        }
    // all B fragments (4 chunks)
    f16x8 bh[4], bl[4];
#pragma unroll
    for (int c = 0; c < 4; ++c) {
        const float* src = (c < 2) ? cten : mten;
        const int ch0 = (c & 1) * 32 + quad * 8;
        const long off = bb + (long)px * 64 + ch0;
        float4 p0 = *(const float4*)(src + off);
        float4 p1 = *(const float4*)(src + off + 4);
        float vv[8] = {p0.x, p0.y, p0.z, p0.w, p1.x, p1.y, p1.z, p1.w};
        split8(vv, &bh[c], &bl[c]);
    }

    floatx4 acc[2];
#pragma unroll
    for (int f = 0; f < 2; ++f) acc[f] = (floatx4){0.f, 0.f, 0.f, 0.f};
#pragma unroll
    for (int c = 0; c < 4; ++c)
#pragma unroll
        for (int f = 0; f < 2; ++f) {
            acc[f] = __builtin_amdgcn_mfma_f32_16x16x32_f16(wh[c][f], bh[c], acc[f], 0, 0, 0);
            acc[f] = __builtin_amdgcn_mfma_f32_16x16x32_f16(wh[c][f], bl[c], acc[f], 0, 0, 0);
            acc[f] = __builtin_amdgcn_mfma_f32_16x16x32_f16(wl[c][f], bh[c], acc[f], 0, 0, 0);
        }

#pragma unroll
    for (int f = 0; f < 2; ++f) {
        const int co = fh * 32 + f * 16 + quad * 4;
        const long off = bb + (long)px * 64 + co;
        float4 ov = *(const float4*)(oten + off);
        float4 hv;
        hv.x = ov.x * tanhf_(acc[f][0] + bias[co + 0]);
        hv.y = ov.y * tanhf_(acc[f][1] + bias[co + 1]);
        hv.z = ov.z * tanhf_(acc[f][2] + bias[co + 2]);
        hv.w = ov.w * tanhf_(acc[f][3] + bias[co + 3]);
        *(float4*)(houtp + off) = hv;
    }
}

// ---------------------------------------------------------------------------
// logits split-K: grid (b, 16 K-chunks of 256 px); partial C[64][64] each.
// ---------------------------------------------------------------------------
__global__ __launch_bounds__(256) void logits_part(
    const float* __restrict__ q, const float* __restrict__ k, float* __restrict__ part)
{
    __shared__ float qs[64][66], ks[64][66];
    const int tid = threadIdx.x;
    const int b = blockIdx.x, kc = blockIdx.y;
    const int cqq = tid >> 4, ckq = tid & 15;
    float pacc[4][4];
#pragma unroll
    for (int u = 0; u < 4; ++u)
#pragma unroll
        for (int v = 0; v < 4; ++v) pacc[u][v] = 0.f;

    for (int sub = 0; sub < 4; ++sub) {
        const int px0 = kc * 256 + sub * 64;
        __syncthreads();
#pragma unroll
        for (int rr = 0; rr < 16; ++rr) {
            const int idx = rr * 256 + tid;
            const int chh = idx >> 6, pxo = idx & 63;
            qs[chh][pxo] = q[((long)b * 64 + chh) * HWN + px0 + pxo];
            ks[chh][pxo] = k[((long)b * 64 + chh) * HWN + px0 + pxo];
        }
        __syncthreads();
        for (int p = 0; p < 64; ++p) {
            float qv[4], kv[4];
#pragma unroll
            for (int u = 0; u < 4; ++u) { qv[u] = qs[cqq + 16 * u][p]; kv[u] = ks[ckq + 16 * u][p]; }
#pragma unroll
            for (int u = 0; u < 4; ++u)
#pragma unroll
                for (int v = 0; v < 4; ++v) pacc[u][v] = fmaf(qv[u], kv[v], pacc[u][v]);
        }
    }
#pragma unroll
    for (int u = 0; u < 4; ++u)
#pragma unroll
        for (int v = 0; v < 4; ++v)
            part[(((long)b * 16 + kc) * 64 + cqq + 16 * u) * 64 + ckq + 16 * v] = pacc[u][v];
}

// reduce 16 partials + softmax; one wave per (b,cq) row
__global__ void reduce_softmax(const float* __restrict__ part, float* __restrict__ attn)
{
    const int row = blockIdx.x;            // b*64 + cq
    const int b = row >> 6, cq = row & 63;
    const int lane = threadIdx.x;
    float s = 0.f;
#pragma unroll
    for (int kc = 0; kc < 16; ++kc)
        s += part[(((long)b * 16 + kc) * 64 + cq) * 64 + lane];
    float v = s * (1.f / 64.f);
    float mx = v;
    for (int off = 32; off; off >>= 1) mx = fmaxf(mx, __shfl_xor(mx, off));
    float e = fexp2_((v - mx) * 1.44269504089f);
    float sum = e;
    for (int off = 32; off; off >>= 1) sum += __shfl_xor(sum, off);
    attn[row * 64 + lane] = e / sum;
}

// out[b,t,c,n] = sum_d attn[b,c,d] * v[t,b,n,d]   (v fp32 channels-last)
__global__ __launch_bounds__(256) void out_cl(
    const float* __restrict__ attn, const float* __restrict__ hs,
    float* __restrict__ outp)
{
    __shared__ __align__(16) float att_t[64][8];
    const int bt = blockIdx.x;
    const int b = bt >> 3, t = bt & 7;
    const int c0 = blockIdx.z * 8;
    const int tid = threadIdx.x;
    for (int i = tid; i < 512; i += 256) {
        int d = i >> 3, j = i & 7;
        att_t[d][j] = attn[(b * 64 + c0 + j) * 64 + d];
    }
    __syncthreads();

    const long px = blockIdx.y * 256 + tid;
    const long SLOT = (long)Bn * HWN * 64;
    const float* vb = hs + (long)t * SLOT + ((long)b * HWN + px) * 64;

    float acc[8];
#pragma unroll
    for (int j = 0; j < 8; ++j) acc[j] = 0.f;
#pragma unroll 4
    for (int dg = 0; dg < 16; ++dg) {
        float4 v4 = *(const float4*)(vb + dg * 4);
        const float* vp = (const float*)&v4;
#pragma unroll
        for (int j4 = 0; j4 < 4; ++j4) {
            const float vv = vp[j4];
            const float4 a0 = *(const float4*)&att_t[dg * 4 + j4][0];
            const float4 a1 = *(const float4*)&att_t[dg * 4 + j4][4];
            acc[0] = fmaf(vv, a0.x, acc[0]); acc[1] = fmaf(vv, a0.y, acc[1]);
            acc[2] = fmaf(vv, a0.z, acc[2]); acc[3] = fmaf(vv, a0.w, acc[3]);
            acc[4] = fmaf(vv, a1.x, acc[4]); acc[5] = fmaf(vv, a1.y, acc[5]);
            acc[6] = fmaf(vv, a1.z, acc[6]); acc[7] = fmaf(vv, a1.w, acc[7]);
        }
    }
    const long ob = ((long)(b * 8 + t) * 64 + c0) * HWN + px;
#pragma unroll
    for (int j = 0; j < 8; ++j) outp[ob + (long)j * HWN] = acc[j];
}

// ---------------------------------------------------------------------------
extern "C" void kernel_launch(void* const* d_in, const int* in_sizes, int n_in,
                              void* d_out, int out_size, void* d_ws, size_t ws_size,
                              hipStream_t stream)
{
    const float* x = (const float*)d_in[0];
    const float* w_rzo[2] = {(const float*)d_in[1],  (const float*)d_in[12]};
    const float* b_rzo[2] = {(const float*)d_in[2],  (const float*)d_in[13]};
    const float* w_rz[2]  = {(const float*)d_in[3],  (const float*)d_in[14]};
    const float* b_rz[2]  = {(const float*)d_in[4],  (const float*)d_in[15]};
    const float* w_h[2]   = {(const float*)d_in[5],  (const float*)d_in[16]};
    const float* b_h[2]   = {(const float*)d_in[6],  (const float*)d_in[17]};
    const float* w_o[2]   = {(const float*)d_in[7],  (const float*)d_in[18]};
    const float* b_o[2]   = {(const float*)d_in[8],  (const float*)d_in[19]};
    const float* td_h[2]  = {(const float*)d_in[9],  (const float*)d_in[20]};
    const float* td_m[2]  = {(const float*)d_in[10], (const float*)d_in[21]};
    const float* tg[2]    = {(const float*)d_in[11], (const float*)d_in[22]};

    // ---- workspace layout (fp32 channels-last activations) ----
    const size_t S64 = (size_t)Bn * HWN * 64;          // 1M floats = 4 MiB
    float* P = (float*)d_ws;
    float* h0    = P; P += S64;
    float* c0    = P; P += S64;
    float* m0    = P; P += S64;
    float* c1    = P; P += S64;
    float* m1    = P; P += S64;
    float* zslab = P; P += S64;                        // zeros; h1prev @ t=0
    float* A_cl  = P; P += (size_t)Bn * HWN * 192;     // 12 MiB (q/k overlay only)
    float* B_cl  = P; P += (size_t)Bn * HWN * 128;     // 8 MiB (gc tables)
    float* rb    = P; P += S64;
    float* xrb   = P; P += S64;
    float* zb    = P; P += S64;
    float* xzb   = P; P += S64;
    float* ogb   = P; P += S64;
    float* rcb   = P; P += S64;
    float* xmb   = P; P += S64;
    float* hs    = P; P += (size_t)Tn * S64;           // 32 MiB
    float* x_cl  = P; P += (size_t)Tn * Bn * HWN * 16; // 8 MiB
    _Float16* wA0 = (_Float16*)P;
    _Float16* wB0 = wA0 + 331776;
    _Float16* wH0 = wB0 + 221184;
    _Float16* wA1 = wH0 + 110592;
    _Float16* wB1 = wA1 + 442368;
    _Float16* wH1 = wB1 + 294912;
    _Float16* wO0 = wH1 + 147456;
    _Float16* wO1 = wO0 + 16384;
    // q/k/partials/attn overlay A_cl (A_cl is never written anymore)
    float* qbuf  = A_cl;
    float* kbuf  = qbuf + S64;                          // 4 MiB
    float* partb = kbuf + S64;                          // 1 MiB
    float* attnb = partb + (size_t)Bn * 16 * 64 * 64;   // 64 KiB
    // gate-constant tables live in the (now unused) B_cl region
    float* gc0   = B_cl;
    float* gc1   = B_cl + 192;

    hipMemsetAsync(h0, 0, 6 * S64 * sizeof(float), stream);

    prep_x_kernel<<<512, 256, 0, stream>>>(x, x_cl);
    prep_gc<<<1, 64, 0, stream>>>(tg[0], td_h[0], td_m[0], gc0);
    prep_gc<<<1, 64, 0, stream>>>(tg[1], td_h[1], td_m[1], gc1);
    PW8 pw;
    pw.p[0] = {w_rzo[0], wA0, 80, 192, 3, 9};
    pw.p[1] = {w_rz[0],  wB0, 80, 128, 3, 9};
    pw.p[2] = {w_h[0],   wH0, 80,  64, 3, 9};
    pw.p[3] = {w_rzo[1], wA1, 128, 192, 4, 9};
    pw.p[4] = {w_rz[1],  wB1, 128, 128, 4, 9};
    pw.p[5] = {w_h[1],   wH1, 128, 64, 4, 9};
    pw.p[6] = {w_o[0],   wO0, 128, 64, 4, 1};
    pw.p[7] = {w_o[1],   wO1, 128, 64, 4, 1};
    prep_w_all<<<dim3(128, 8), 256, 0, stream>>>(pw);

    for (int t = 0; t < Tn; ++t) {
        const float* xt = x_cl + (size_t)t * Bn * HWN * 16;
        const float* h1prev = (t == 0) ? zslab : (hs + (size_t)(t - 1) * S64);
        float* h1out = hs + (size_t)t * S64;
        const int lastq = (t == Tn - 1) ? 1 : 0;

        // ---------- layer 0: inp=x_t, h=h0, c=c0, m_in=m1 -> m_out=m0 ----------
        conv3m<0, 2, 8><<<dim3(32, 10, 4), 256, 0, stream>>>(
            xt, 16, h0, m1, 80, 3,
            wA0, b_rzo[0], nullptr, 192, 12,
            wB0, b_rz[0],  nullptr, 128, 8, 6,
            rcb, xmb, zb, xzb, ogb, rb, xrb, c0,
            gc0, 0);
        conv3m<1, 1, 8><<<dim3(32, 4, 8), 256, 0, stream>>>(
            xt, 16, rcb, xmb, 80, 3,
            wH0, b_h[0], c0, 64, 4,
            wH0, b_h[0], m0, 64, 4, 0,
            zb, xzb, c0, m1, rb, xrb, qbuf, kbuf,
            nullptr, 0);
        conv1x1m<<<dim3(128, 4), 256, 0, stream>>>(c0, m0, ogb, wO0, b_o[0], h0);

        // ---------- layer 1: inp=h0, h=hs[t-1], c=c1, m_in=m0 -> m_out=m1 -------
        conv3m<0, 2, 8><<<dim3(32, 10, 4), 256, 0, stream>>>(
            h0, 64, h1prev, m0, 128, 4,
            wA1, b_rzo[1], nullptr, 192, 12,
            wB1, b_rz[1],  nullptr, 128, 8, 6,
            rcb, xmb, zb, xzb, ogb, rb, xrb, c1,
            gc1, lastq);
        conv3m<1, 1, 8><<<dim3(32, 4, 8), 256, 0, stream>>>(
            h0, 64, rcb, xmb, 128, 4,
            wH1, b_h[1], c1, 64, 4,
            wH1, b_h[1], m1, 64, 4, 0,
            zb, xzb, c1, m0, rb, xrb, qbuf, kbuf,
            nullptr, lastq);
        conv1x1m<<<dim3(128, 4), 256, 0, stream>>>(c1, m1, ogb, wO1, b_o[1], h1out);
    }

    // ---------- attention ----------
    logits_part<<<dim3(4, 16), 256, 0, stream>>>(qbuf, kbuf, partb);
    reduce_softmax<<<256, 64, 0, stream>>>(partb, attnb);
    out_cl<<<dim3(32, 16, 8), 256, 0, stream>>>(attnb, hs, (float*)d_out);
}

// Round 14
// 1182.649 us; speedup vs baseline: 1.0180x; 1.0180x over previous
//
#include <hip/hip_runtime.h>
#include <math.h>

#define HWN 4096
#define Bn 4
#define Tn 8

typedef __attribute__((ext_vector_type(8))) _Float16 f16x8;
typedef __attribute__((ext_vector_type(4))) float floatx4;

// fast HW transcendentals: v_exp_f32 / v_rcp_f32 (no OCML branchy calls)
__device__ __forceinline__ float fexp2_(float x) { return __builtin_amdgcn_exp2f(x); }
__device__ __forceinline__ float frcp_(float x)  { return __builtin_amdgcn_rcpf(x); }
__device__ __forceinline__ float sigmoidf_(float v) {
    return frcp_(1.f + fexp2_(v * -1.44269504089f));
}
__device__ __forceinline__ float tanhf_(float v) {
    float vc = fminf(fmaxf(v, -15.f), 15.f);      // avoid inf/inf NaN
    float t = fexp2_(vc * 2.88539008178f);        // e^(2v)
    return (t - 1.f) * frcp_(t + 1.f);
}

// split 8 fp32 -> f16 hi/lo vectors (value = hi + lo, ~22-bit effective)
__device__ __forceinline__ void split8(const float* vv, f16x8* hi, f16x8* lo) {
#pragma unroll
    for (int j = 0; j < 8; ++j) {
        _Float16 h = (_Float16)vv[j];
        (*hi)[j] = h;
        (*lo)[j] = (_Float16)(vv[j] - (float)h);
    }
}

// ---------------------------------------------------------------------------
// Weight prep (ALL tensors in one dispatch): fp32 [Cout][Ctot][KK] ->
// A-fragment-swizzled split-f16 [plane][kk][chunk][cog][lane][j].
// blockIdx.y selects the tensor descriptor.
// ---------------------------------------------------------------------------
struct PW  { const float* W; _Float16* dst; int Ctot, Cout, nch, KK; };
struct PW8 { PW p[8]; };

__global__ __launch_bounds__(256) void prep_w_all(PW8 d)
{
    const PW e = d.p[blockIdx.y];
    const int ncog = e.Cout >> 4;
    const long total = (long)e.KK * e.nch * ncog * 512;
    for (long i = (long)blockIdx.x * 256 + threadIdx.x; i < total;
         i += (long)gridDim.x * 256) {
        int j    = (int)(i & 7);
        int lane = (int)((i >> 3) & 63);
        long r   = i >> 9;
        int f = (int)(r % ncog); r /= ncog;
        int c = (int)(r % e.nch);  r /= e.nch;
        int kk = (int)r;
        int co = f * 16 + (lane & 15);
        int ci = c * 32 + (lane >> 4) * 8 + j;
        float v = (ci < e.Ctot) ? e.W[((long)co * e.Ctot + ci) * e.KK + kk] : 0.f;
        _Float16 hi = (_Float16)v;
        e.dst[i]         = hi;
        e.dst[total + i] = (_Float16)(v - (float)hi);
    }
}

// x fp32 [b][t][16][4096] -> x_cl fp32 [t][b][px][16]
__global__ __launch_bounds__(256) void prep_x_kernel(
    const float* __restrict__ x, float* __restrict__ xcl)
{
    const int i = blockIdx.x * 256 + threadIdx.x;     // 131072 total
    const int px = i & 4095;
    const int t  = (i >> 12) & 7;
    const int b  = i >> 15;
    float* d = xcl + (((long)t * Bn + b) * HWN + px) * 16;
#pragma unroll
    for (int ch = 0; ch < 16; ++ch)
        d[ch] = x[((long)(b * 8 + t) * 16 + ch) * HWN + px];
}

// gate constants for BOTH layers in one dispatch (blockIdx.x = layer):
// gc[0..63]=sigmoid(tg), [64..127]=exp(-td_h), [128..191]=exp(-td_m).
__global__ void prep_gc2(const float* __restrict__ tg0, const float* __restrict__ tdh0,
                         const float* __restrict__ tdm0, float* __restrict__ gc0,
                         const float* __restrict__ tg1, const float* __restrict__ tdh1,
                         const float* __restrict__ tdm1, float* __restrict__ gc1)
{
    const int j = threadIdx.x;
    const float* tg  = blockIdx.x ? tg1  : tg0;
    const float* tdh = blockIdx.x ? tdh1 : tdh0;
    const float* tdm = blockIdx.x ? tdm1 : tdm0;
    float* gc        = blockIdx.x ? gc1  : gc0;
    gc[j]       = 1.f / (1.f + expf(-tg[j]));
    gc[64 + j]  = expf(-tdh[j]);
    gc[128 + j] = expf(-tdm[j]);
}

// ---------------------------------------------------------------------------
// MFMA implicit-GEMM 3x3 SAME conv. fp32 channels-last activations; hi/lo
// f16 split done while writing LDS. TR = tile rows; 4 waves, G=TR/4 rows/wave.
//  - LDS tile [TR+2][18][2][40]; kx-outer tap loop with (G+2)-row reg cache
//  - weight 5-deep ring, 4-ahead prefetch; staging prefetch at end of kx==1
// EPI=0: A/B conv merged dispatch + FUSED GATES EPILOGUE. TR=16 (measured
//        best r12; TR=8 raised occupancy 13->21% but regressed total r13 —
//        family is chunk-chain latency-bound, not TLP-bound; closed).
// EPI=1: H-conv: tanh + fused state update (+ q/k on last cell). TR=8,NF=1,
//        grid (32,4,8)=1024 blocks (r12 win).
// ---------------------------------------------------------------------------
template<int EPI, int NF, int TR>
__global__ __launch_bounds__(256) void conv3m(
    const float* __restrict__ in1, int C1,
    const float* __restrict__ in2a, const float* __restrict__ in2b,
    int Ctot, int nch,
    const _Float16* __restrict__ wA, const float* __restrict__ biasA,
    float* outA, int CoutA, int ncogA,
    const _Float16* __restrict__ wB, const float* __restrict__ biasB,
    float* outB, int CoutB, int ncogB, int nA,
    float* s1, float* s2, float* s3, float* s4,
    float* s5, float* s6, float* s7, float* s8,
    const float* __restrict__ gc, int last)
{
    constexpr int G = TR / 4;                       // rows per wave
    constexpr int SLOTS = (TR + 2) * 18 * 4;        // staging slots (8ch each)
    constexpr int NS = (SLOTS + 255) / 256;         // per-thread staging iters
    __shared__ __align__(16) _Float16 ldsB[TR + 2][18][2][40];

    const int tid = threadIdx.x;
    const int ty0 = (blockIdx.x >> 2) * TR;
    const int tx0 = (blockIdx.x & 3) * 16;
    const int b   = blockIdx.z & 3;
    const int which = (EPI == 1) ? (int)(blockIdx.z >> 2)
                                 : (blockIdx.y >= (unsigned)nA ? 1 : 0);

    const float*    in2  = which ? in2b : in2a;
    const _Float16* Wf   = which ? wB : wA;
    const float*    bias = which ? biasB : biasA;
    float*          outp = which ? outB : outA;
    const int Cout = which ? CoutB : CoutA;
    const int ncog = which ? ncogB : ncogA;
    const int cog0 = (EPI == 1) ? blockIdx.y * NF
                   : (which ? (blockIdx.y - nA) * NF : blockIdx.y * NF);
    const int co0  = cog0 * 16;

    const int lane = tid & 63, wv = tid >> 6, tl = lane & 15, quad = lane >> 4;
    const int C2 = Ctot - C1;
    const long wplane = (long)9 * nch * ncog * 512;
    const float* in1b  = in1 + (long)b * HWN * C1;
    const float* in2bb = in2 + (long)b * HWN * C2;

    floatx4 acc[NF][G];
#pragma unroll
    for (int f = 0; f < NF; ++f)
#pragma unroll
        for (int g = 0; g < G; ++g) acc[f][g] = (floatx4){0.f, 0.f, 0.f, 0.f};

    // staging prefetch registers (next chunk's 8-ch groups)
    float4 pa[NS], pb[NS];
    auto prefetch = [&](int c) {
        const int c0 = c * 32;
#pragma unroll
        for (int s = 0; s < NS; ++s) {
            const int i = tid + s * 256;
            float4 va = {0.f, 0.f, 0.f, 0.f}, vb = {0.f, 0.f, 0.f, 0.f};
            if (i < SLOTS) {
                const int pxh = i >> 2, cig = i & 3;
                const int yh = pxh / 18, xh = pxh - yh * 18;
                const int y = ty0 + yh - 1, x = tx0 + xh - 1;
                const int ch = c0 + cig * 8;
                if (ch < Ctot && (unsigned)y < 64u && (unsigned)x < 64u) {
                    const float* src; long off;
                    if (ch < C1) { src = in1b;  off = (long)(y * 64 + x) * C1 + ch; }
                    else         { src = in2bb; off = (long)(y * 64 + x) * C2 + ch - C1; }
                    va = *(const float4*)(src + off);
                    vb = *(const float4*)(src + off + 4);
                }
            }
            pa[s] = va; pb[s] = vb;
        }
    };

    prefetch(0);

    for (int c = 0; c < nch; ++c) {
        // weight tap step s covers tap kk=(s%3)*3+s/3 (kx-outer order);
        // 5-deep ring, 4-ahead. Steps 0..3 issued before the barriers.
        f16x8 wh[5][NF], wl[5][NF];
#define LOADW(S, BUF)                                                           \
        {                                                                       \
            const int kk_ = ((S) % 3) * 3 + (S) / 3;                            \
            const long wo_ = ((long)(kk_ * nch + c) * ncog + cog0) * 512 + lane * 8; \
            _Pragma("unroll")                                                   \
            for (int f = 0; f < NF; ++f) {                                      \
                wh[BUF][f] = *(const f16x8*)(Wf + wo_ + (long)f * 512);         \
                wl[BUF][f] = *(const f16x8*)(Wf + wplane + wo_ + (long)f * 512);\
            }                                                                   \
        }
        LOADW(0, 0)
        LOADW(1, 1)
        LOADW(2, 2)
        LOADW(3, 3)

        __syncthreads();                     // protect LDS from prior readers
        // store prefetched chunk to LDS (split fp32 -> f16 hi/lo)
#pragma unroll
        for (int s = 0; s < NS; ++s) {
            const int i = tid + s * 256;
            if (i < SLOTS) {
                const int pxh = i >> 2, cig = i & 3;
                const int yh = pxh / 18, xh = pxh - yh * 18;
                float vv[8] = {pa[s].x, pa[s].y, pa[s].z, pa[s].w,
                               pb[s].x, pb[s].y, pb[s].z, pb[s].w};
                f16x8 vh, vl;
                split8(vv, &vh, &vl);
                *(f16x8*)&ldsB[yh][xh][0][cig * 8] = vh;
                *(f16x8*)&ldsB[yh][xh][1][cig * 8] = vl;
            }
        }
        __syncthreads();

        // tap loop: kx outer, (G+2)-row register cache reused across ky.
#pragma unroll
        for (int kx = 0; kx < 3; ++kx) {
            f16x8 rh[G + 2], rl[G + 2];
#pragma unroll
            for (int rr = 0; rr < G + 2; ++rr) {
                const _Float16* pB = &ldsB[wv * G + rr][tl + kx][0][quad * 8];
                rh[rr] = *(const f16x8*)pB;
                rl[rr] = *(const f16x8*)(pB + 40);
            }
#pragma unroll
            for (int ky = 0; ky < 3; ++ky) {
                const int s = kx * 3 + ky;
                if (s < 5) LOADW(s + 4, (s + 4) % 5)
                const int cur = s % 5;
#pragma unroll
                for (int f = 0; f < NF; ++f)
#pragma unroll
                    for (int g = 0; g < G; ++g) {
                        acc[f][g] = __builtin_amdgcn_mfma_f32_16x16x32_f16(wh[cur][f], rh[g + ky], acc[f][g], 0, 0, 0);
                        acc[f][g] = __builtin_amdgcn_mfma_f32_16x16x32_f16(wh[cur][f], rl[g + ky], acc[f][g], 0, 0, 0);
                        acc[f][g] = __builtin_amdgcn_mfma_f32_16x16x32_f16(wl[cur][f], rh[g + ky], acc[f][g], 0, 0, 0);
                    }
            }
            // issue next chunk's staging loads AFTER all weight loads of
            // this chunk -> vmcnt waits on weights stay clean.
            if (kx == 1 && c + 1 < nch) prefetch(c + 1);
        }
#undef LOADW
    }

    // epilogue: C/D layout col(px)=lane&15, row(co)=quad*4+reg
    if (EPI == 0) {
        // fused gates: gid uniform per block (32-cout span never crosses 64)
        const int gid = co0 >> 6;
        const long bb64 = (long)b * HWN * 64;
        const float* dec = which ? in2b : in2a;            // m or h (base)
        const float* cs  = (const float*)s8;               // c state (base)
        float* g0   = which ? s2 : s1;                     // xm : rc
        float* g1   = which ? s4 : s3;                     // xz : z
        float* rout = which ? s7 : s6;                     // xr : r
#pragma unroll
        for (int f = 0; f < NF; ++f) {
            const int co = co0 + f * 16 + quad * 4;
            const int ch = co & 63;
            float gvc[4], dvc[4];
            if (gid < 2) {
#pragma unroll
                for (int j = 0; j < 4; ++j) {
                    gvc[j] = gc[ch + j];
                    dvc[j] = gc[(which ? 128 : 64) + ch + j];
                }
            }
#pragma unroll
            for (int g = 0; g < G; ++g) {
                const long px = (long)(ty0 + wv * G + g) * 64 + tx0 + tl;
                const long off = bb64 + px * 64 + ch;
                float vv[4];
                vv[0] = acc[f][g][0] + bias[co + 0];
                vv[1] = acc[f][g][1] + bias[co + 1];
                vv[2] = acc[f][g][2] + bias[co + 2];
                vv[3] = acc[f][g][3] + bias[co + 3];
                if (gid == 2) {
                    float ov[4];
#pragma unroll
                    for (int j = 0; j < 4; ++j) ov[j] = sigmoidf_(vv[j]);
                    *(float4*)(s5 + off) = *(float4*)ov;
                } else {
                    float4 dv = *(const float4*)(dec + off);
                    const float* dvp = (const float*)&dv;
                    float rr[4];
#pragma unroll
                    for (int j = 0; j < 4; ++j)
                        rr[j] = sigmoidf_(vv[j] * gvc[j] + dvp[j] * dvc[j]);
                    if (gid == 0) {
                        float4 sv = dv;
                        if (!which) sv = *(const float4*)(cs + off);
                        const float* svp = (const float*)&sv;
                        float outv[4];
#pragma unroll
                        for (int j = 0; j < 4; ++j) outv[j] = rr[j] * svp[j];
                        *(float4*)(g0 + off) = *(float4*)outv;
                        if (last) *(float4*)(rout + off) = *(float4*)rr;
                    } else {
                        *(float4*)(g1 + off) = *(float4*)rr;
                    }
                }
            }
        }
    } else {
        const float* zt = which ? s2 : s1;
        const float* st = which ? s4 : s3;
        float* qk = which ? s8 : s7;
#pragma unroll
        for (int f = 0; f < NF; ++f) {
            const int co = co0 + f * 16 + quad * 4;
#pragma unroll
            for (int g = 0; g < G; ++g) {
                const long px = (long)(ty0 + wv * G + g) * 64 + tx0 + tl;
                const long off = (long)b * HWN * 64 + px * 64 + co;
                float4 zv = *(const float4*)(zt + off);
                float4 sv = *(const float4*)(st + off);
                float gv[4], cn[4];
                gv[0] = tanhf_(acc[f][g][0] + bias[co + 0]);
                gv[1] = tanhf_(acc[f][g][1] + bias[co + 1]);
                gv[2] = tanhf_(acc[f][g][2] + bias[co + 2]);
                gv[3] = tanhf_(acc[f][g][3] + bias[co + 3]);
                cn[0] = zv.x * sv.x + (1.f - zv.x) * gv[0];
                cn[1] = zv.y * sv.y + (1.f - zv.y) * gv[1];
                cn[2] = zv.z * sv.z + (1.f - zv.z) * gv[2];
                cn[3] = zv.w * sv.w + (1.f - zv.w) * gv[3];
                *(float4*)(outp + off) = *(float4*)cn;
                if (last) {
                    float4 rv = *(const float4*)(s5 + off);
                    float4 xv = *(const float4*)(s6 + off);
                    qk[((long)(b * 64) + co + 0) * HWN + px] = 0.25f * (rv.x + xv.x + cn[0] + gv[0]);
                    qk[((long)(b * 64) + co + 1) * HWN + px] = 0.25f * (rv.y + xv.y + cn[1] + gv[1]);
                    qk[((long)(b * 64) + co + 2) * HWN + px] = 0.25f * (rv.z + xv.z + cn[2] + gv[2]);
                    qk[((long)(b * 64) + co + 3) * HWN + px] = 0.25f * (rv.w + xv.w + cn[3] + gv[3]);
                }
            }
        }
    }
}

// ---------------------------------------------------------------------------
// 1x1 conv (MFMA) over concat([c,m]) fp32-cl -> h = o * tanh(conv + bias).
// Each wave: 16 px x 32 couts; grid (128, B) = 512 blocks = 2048 waves.
// ---------------------------------------------------------------------------
__global__ __launch_bounds__(256) void conv1x1m(
    const float* __restrict__ cten, const float* __restrict__ mten,
    const float* __restrict__ oten,
    const _Float16* __restrict__ W, const float* __restrict__ bias,
    float* houtp)
{
    const int tid = threadIdx.x;
    const int lane = tid & 63, wv = tid >> 6, tl = lane & 15, quad = lane >> 4;
    const int b = blockIdx.y;
    const int fh = blockIdx.x & 1;                 // cout half: 0..31 / 32..63
    const int px = (blockIdx.x >> 1) * 64 + wv * 16 + tl;
    const long bb = (long)b * HWN * 64;

    // weight fragments (4 chunks x 2 cout-frags of this half, hi+lo)
    f16x8 wh[4][2], wl[4][2];
#pragma unroll
    for (int c = 0; c < 4; ++c)
#pragma unroll
        for (int f = 0; f < 2; ++f) {
            const long wo = (long)(c * 4 + fh * 2 + f) * 512 + lane * 8;
            wh[c][f] = *(const f16x8*)(W + wo);
            wl[c][f] = *(const f16x8*)(W + 8192 + wo);
        }
    // all B fragments (4 chunks)
    f16x8 bh[4], bl[4];
#pragma unroll
    for (int c = 0; c < 4; ++c) {
        const float* src = (c < 2) ? cten : mten;
        const int ch0 = (c & 1) * 32 + quad * 8;
        const long off = bb + (long)px * 64 + ch0;
        float4 p0 = *(const float4*)(src + off);
        float4 p1 = *(const float4*)(src + off + 4);
        float vv[8] = {p0.x, p0.y, p0.z, p0.w, p1.x, p1.y, p1.z, p1.w};
        split8(vv, &bh[c], &bl[c]);
    }

    floatx4 acc[2];
#pragma unroll
    for (int f = 0; f < 2; ++f) acc[f] = (floatx4){0.f, 0.f, 0.f, 0.f};
#pragma unroll
    for (int c = 0; c < 4; ++c)
#pragma unroll
        for (int f = 0; f < 2; ++f) {
            acc[f] = __builtin_amdgcn_mfma_f32_16x16x32_f16(wh[c][f], bh[c], acc[f], 0, 0, 0);
            acc[f] = __builtin_amdgcn_mfma_f32_16x16x32_f16(wh[c][f], bl[c], acc[f], 0, 0, 0);
            acc[f] = __builtin_amdgcn_mfma_f32_16x16x32_f16(wl[c][f], bh[c], acc[f], 0, 0, 0);
        }

#pragma unroll
    for (int f = 0; f < 2; ++f) {
        const int co = fh * 32 + f * 16 + quad * 4;
        const long off = bb + (long)px * 64 + co;
        float4 ov = *(const float4*)(oten + off);
        float4 hv;
        hv.x = ov.x * tanhf_(acc[f][0] + bias[co + 0]);
        hv.y = ov.y * tanhf_(acc[f][1] + bias[co + 1]);
        hv.z = ov.z * tanhf_(acc[f][2] + bias[co + 2]);
        hv.w = ov.w * tanhf_(acc[f][3] + bias[co + 3]);
        *(float4*)(houtp + off) = hv;
    }
}

// ---------------------------------------------------------------------------
// logits split-K: grid (b, 16 K-chunks of 256 px); partial C[64][64] each.
// ---------------------------------------------------------------------------
__global__ __launch_bounds__(256) void logits_part(
    const float* __restrict__ q, const float* __restrict__ k, float* __restrict__ part)
{
    __shared__ float qs[64][66], ks[64][66];
    const int tid = threadIdx.x;
    const int b = blockIdx.x, kc = blockIdx.y;
    const int cqq = tid >> 4, ckq = tid & 15;
    float pacc[4][4];
#pragma unroll
    for (int u = 0; u < 4; ++u)
#pragma unroll
        for (int v = 0; v < 4; ++v) pacc[u][v] = 0.f;

    for (int sub = 0; sub < 4; ++sub) {
        const int px0 = kc * 256 + sub * 64;
        __syncthreads();
#pragma unroll
        for (int rr = 0; rr < 16; ++rr) {
            const int idx = rr * 256 + tid;
            const int chh = idx >> 6, pxo = idx & 63;
            qs[chh][pxo] = q[((long)b * 64 + chh) * HWN + px0 + pxo];
            ks[chh][pxo] = k[((long)b * 64 + chh) * HWN + px0 + pxo];
        }
        __syncthreads();
        for (int p = 0; p < 64; ++p) {
            float qv[4], kv[4];
#pragma unroll
            for (int u = 0; u < 4; ++u) { qv[u] = qs[cqq + 16 * u][p]; kv[u] = ks[ckq + 16 * u][p]; }
#pragma unroll
            for (int u = 0; u < 4; ++u)
#pragma unroll
                for (int v = 0; v < 4; ++v) pacc[u][v] = fmaf(qv[u], kv[v], pacc[u][v]);
        }
    }
#pragma unroll
    for (int u = 0; u < 4; ++u)
#pragma unroll
        for (int v = 0; v < 4; ++v)
            part[(((long)b * 16 + kc) * 64 + cqq + 16 * u) * 64 + ckq + 16 * v] = pacc[u][v];
}

// reduce 16 partials + softmax; one wave per (b,cq) row
__global__ void reduce_softmax(const float* __restrict__ part, float* __restrict__ attn)
{
    const int row = blockIdx.x;            // b*64 + cq
    const int b = row >> 6, cq = row & 63;
    const int lane = threadIdx.x;
    float s = 0.f;
#pragma unroll
    for (int kc = 0; kc < 16; ++kc)
        s += part[(((long)b * 16 + kc) * 64 + cq) * 64 + lane];
    float v = s * (1.f / 64.f);
    float mx = v;
    for (int off = 32; off; off >>= 1) mx = fmaxf(mx, __shfl_xor(mx, off));
    float e = fexp2_((v - mx) * 1.44269504089f);
    float sum = e;
    for (int off = 32; off; off >>= 1) sum += __shfl_xor(sum, off);
    attn[row * 64 + lane] = e / sum;
}

// out[b,t,c,n] = sum_d attn[b,c,d] * v[t,b,n,d]   (v fp32 channels-last)
__global__ __launch_bounds__(256) void out_cl(
    const float* __restrict__ attn, const float* __restrict__ hs,
    float* __restrict__ outp)
{
    __shared__ __align__(16) float att_t[64][8];
    const int bt = blockIdx.x;
    const int b = bt >> 3, t = bt & 7;
    const int c0 = blockIdx.z * 8;
    const int tid = threadIdx.x;
    for (int i = tid; i < 512; i += 256) {
        int d = i >> 3, j = i & 7;
        att_t[d][j] = attn[(b * 64 + c0 + j) * 64 + d];
    }
    __syncthreads();

    const long px = blockIdx.y * 256 + tid;
    const long SLOT = (long)Bn * HWN * 64;
    const float* vb = hs + (long)t * SLOT + ((long)b * HWN + px) * 64;

    float acc[8];
#pragma unroll
    for (int j = 0; j < 8; ++j) acc[j] = 0.f;
#pragma unroll 4
    for (int dg = 0; dg < 16; ++dg) {
        float4 v4 = *(const float4*)(vb + dg * 4);
        const float* vp = (const float*)&v4;
#pragma unroll
        for (int j4 = 0; j4 < 4; ++j4) {
            const float vv = vp[j4];
            const float4 a0 = *(const float4*)&att_t[dg * 4 + j4][0];
            const float4 a1 = *(const float4*)&att_t[dg * 4 + j4][4];
            acc[0] = fmaf(vv, a0.x, acc[0]); acc[1] = fmaf(vv, a0.y, acc[1]);
            acc[2] = fmaf(vv, a0.z, acc[2]); acc[3] = fmaf(vv, a0.w, acc[3]);
            acc[4] = fmaf(vv, a1.x, acc[4]); acc[5] = fmaf(vv, a1.y, acc[5]);
            acc[6] = fmaf(vv, a1.z, acc[6]); acc[7] = fmaf(vv, a1.w, acc[7]);
        }
    }
    const long ob = ((long)(b * 8 + t) * 64 + c0) * HWN + px;
#pragma unroll
    for (int j = 0; j < 8; ++j) outp[ob + (long)j * HWN] = acc[j];
}

// ---------------------------------------------------------------------------
extern "C" void kernel_launch(void* const* d_in, const int* in_sizes, int n_in,
                              void* d_out, int out_size, void* d_ws, size_t ws_size,
                              hipStream_t stream)
{
    const float* x = (const float*)d_in[0];
    const float* w_rzo[2] = {(const float*)d_in[1],  (const float*)d_in[12]};
    const float* b_rzo[2] = {(const float*)d_in[2],  (const float*)d_in[13]};
    const float* w_rz[2]  = {(const float*)d_in[3],  (const float*)d_in[14]};
    const float* b_rz[2]  = {(const float*)d_in[4],  (const float*)d_in[15]};
    const float* w_h[2]   = {(const float*)d_in[5],  (const float*)d_in[16]};
    const float* b_h[2]   = {(const float*)d_in[6],  (const float*)d_in[17]};
    const float* w_o[2]   = {(const float*)d_in[7],  (const float*)d_in[18]};
    const float* b_o[2]   = {(const float*)d_in[8],  (const float*)d_in[19]};
    const float* td_h[2]  = {(const float*)d_in[9],  (const float*)d_in[20]};
    const float* td_m[2]  = {(const float*)d_in[10], (const float*)d_in[21]};
    const float* tg[2]    = {(const float*)d_in[11], (const float*)d_in[22]};

    // ---- workspace layout (fp32 channels-last activations) ----
    const size_t S64 = (size_t)Bn * HWN * 64;          // 1M floats = 4 MiB
    float* P = (float*)d_ws;
    float* h0    = P; P += S64;
    float* c0    = P; P += S64;
    float* m0    = P; P += S64;
    float* c1    = P; P += S64;
    float* m1    = P; P += S64;
    float* zslab = P; P += S64;                        // zeros; h1prev @ t=0
    float* A_cl  = P; P += (size_t)Bn * HWN * 192;     // 12 MiB (q/k overlay only)
    float* B_cl  = P; P += (size_t)Bn * HWN * 128;     // 8 MiB (gc tables)
    float* rb    = P; P += S64;
    float* xrb   = P; P += S64;
    float* zb    = P; P += S64;
    float* xzb   = P; P += S64;
    float* ogb   = P; P += S64;
    float* rcb   = P; P += S64;
    float* xmb   = P; P += S64;
    float* hs    = P; P += (size_t)Tn * S64;           // 32 MiB
    float* x_cl  = P; P += (size_t)Tn * Bn * HWN * 16; // 8 MiB
    _Float16* wA0 = (_Float16*)P;
    _Float16* wB0 = wA0 + 331776;
    _Float16* wH0 = wB0 + 221184;
    _Float16* wA1 = wH0 + 110592;
    _Float16* wB1 = wA1 + 442368;
    _Float16* wH1 = wB1 + 294912;
    _Float16* wO0 = wH1 + 147456;
    _Float16* wO1 = wO0 + 16384;
    // q/k/partials/attn overlay A_cl (A_cl is never written anymore)
    float* qbuf  = A_cl;
    float* kbuf  = qbuf + S64;                          // 4 MiB
    float* partb = kbuf + S64;                          // 1 MiB
    float* attnb = partb + (size_t)Bn * 16 * 64 * 64;   // 64 KiB
    // gate-constant tables live in the (now unused) B_cl region
    float* gc0   = B_cl;
    float* gc1   = B_cl + 192;

    hipMemsetAsync(h0, 0, 6 * S64 * sizeof(float), stream);

    prep_x_kernel<<<512, 256, 0, stream>>>(x, x_cl);
    prep_gc2<<<2, 64, 0, stream>>>(tg[0], td_h[0], td_m[0], gc0,
                                   tg[1], td_h[1], td_m[1], gc1);
    PW8 pw;
    pw.p[0] = {w_rzo[0], wA0, 80, 192, 3, 9};
    pw.p[1] = {w_rz[0],  wB0, 80, 128, 3, 9};
    pw.p[2] = {w_h[0],   wH0, 80,  64, 3, 9};
    pw.p[3] = {w_rzo[1], wA1, 128, 192, 4, 9};
    pw.p[4] = {w_rz[1],  wB1, 128, 128, 4, 9};
    pw.p[5] = {w_h[1],   wH1, 128, 64, 4, 9};
    pw.p[6] = {w_o[0],   wO0, 128, 64, 4, 1};
    pw.p[7] = {w_o[1],   wO1, 128, 64, 4, 1};
    prep_w_all<<<dim3(128, 8), 256, 0, stream>>>(pw);

    for (int t = 0; t < Tn; ++t) {
        const float* xt = x_cl + (size_t)t * Bn * HWN * 16;
        const float* h1prev = (t == 0) ? zslab : (hs + (size_t)(t - 1) * S64);
        float* h1out = hs + (size_t)t * S64;
        const int lastq = (t == Tn - 1) ? 1 : 0;

        // ---------- layer 0: inp=x_t, h=h0, c=c0, m_in=m1 -> m_out=m0 ----------
        conv3m<0, 2, 16><<<dim3(16, 10, 4), 256, 0, stream>>>(
            xt, 16, h0, m1, 80, 3,
            wA0, b_rzo[0], nullptr, 192, 12,
            wB0, b_rz[0],  nullptr, 128, 8, 6,
            rcb, xmb, zb, xzb, ogb, rb, xrb, c0,
            gc0, 0);
        conv3m<1, 1, 8><<<dim3(32, 4, 8), 256, 0, stream>>>(
            xt, 16, rcb, xmb, 80, 3,
            wH0, b_h[0], c0, 64, 4,
            wH0, b_h[0], m0, 64, 4, 0,
            zb, xzb, c0, m1, rb, xrb, qbuf, kbuf,
            nullptr, 0);
        conv1x1m<<<dim3(128, 4), 256, 0, stream>>>(c0, m0, ogb, wO0, b_o[0], h0);

        // ---------- layer 1: inp=h0, h=hs[t-1], c=c1, m_in=m0 -> m_out=m1 -------
        conv3m<0, 2, 16><<<dim3(16, 10, 4), 256, 0, stream>>>(
            h0, 64, h1prev, m0, 128, 4,
            wA1, b_rzo[1], nullptr, 192, 12,
            wB1, b_rz[1],  nullptr, 128, 8, 6,
            rcb, xmb, zb, xzb, ogb, rb, xrb, c1,
            gc1, lastq);
        conv3m<1, 1, 8><<<dim3(32, 4, 8), 256, 0, stream>>>(
            h0, 64, rcb, xmb, 128, 4,
            wH1, b_h[1], c1, 64, 4,
            wH1, b_h[1], m1, 64, 4, 0,
            zb, xzb, c1, m0, rb, xrb, qbuf, kbuf,
            nullptr, lastq);
        conv1x1m<<<dim3(128, 4), 256, 0, stream>>>(c1, m1, ogb, wO1, b_o[1], h1out);
    }

    // ---------- attention ----------
    logits_part<<<dim3(4, 16), 256, 0, stream>>>(qbuf, kbuf, partb);
    reduce_softmax<<<256, 64, 0, stream>>>(partb, attnb);
    out_cl<<<dim3(32, 16, 8), 256, 0, stream>>>(attnb, hs, (float*)d_out);
}